// Round 1
// baseline (27013.760 us; speedup 1.0000x reference)
//
#include <hip/hip_runtime.h>
#include <cstdint>
#include <cstddef>

#define SEQ 256
#define BATCH 128
#define HID 1024
#define H3 3072

typedef __bf16 bf16x8 __attribute__((ext_vector_type(8)));
typedef float f32x4 __attribute__((ext_vector_type(4)));

static __device__ __forceinline__ unsigned short f2bf(float f){
  unsigned int u = __float_as_uint(f);
  u += 0x7fffu + ((u >> 16) & 1u);
  return (unsigned short)(u >> 16);
}
static __device__ __forceinline__ bf16x8 ldbf8(const unsigned short* p){
  return *reinterpret_cast<const bf16x8*>(p);
}
static __device__ __forceinline__ float sigm(float x){
  return 1.0f / (1.0f + __expf(-x));
}
static __device__ __forceinline__ float tanh_(float x){
  x = fminf(15.0f, fmaxf(-15.0f, x));
  float e = __expf(2.0f * x);
  return (e - 1.0f) / (e + 1.0f);
}

// ---------------- weight / embedding prep ----------------

__global__ __launch_bounds__(256) void cvt_bf16(const float* __restrict__ in,
                                                unsigned short* __restrict__ out, int n4){
  int i = blockIdx.x * blockDim.x + threadIdx.x;
  int stride = gridDim.x * blockDim.x;
  for (; i < n4; i += stride){
    float4 v = reinterpret_cast<const float4*>(in)[i];
    ushort4 o = { f2bf(v.x), f2bf(v.y), f2bf(v.z), f2bf(v.w) };
    reinterpret_cast<ushort4*>(out)[i] = o;
  }
}

// x0[s*BATCH + b][e] = bf16(emb_W[source[b][s]][e])
__global__ __launch_bounds__(256) void embed_gather(const int* __restrict__ src,
                                                    const float* __restrict__ embW,
                                                    unsigned short* __restrict__ x0){
  int bx = blockIdx.x;            // = s*BATCH + b
  int s = bx >> 7, b = bx & 127;
  int row = src[b * SEQ + s];
  float4 v = reinterpret_cast<const float4*>(embW + (size_t)row * HID)[threadIdx.x];
  ushort4 o = { f2bf(v.x), f2bf(v.y), f2bf(v.z), f2bf(v.w) };
  reinterpret_cast<ushort4*>(x0 + (size_t)bx * HID)[threadIdx.x] = o;
}

// ---------------- one GRU time step ----------------
// Wave tile: 64 batch rows (4 MFMA row-tiles) x 16 cols x 3 gates.
// A-frag (x or h rows) : lane holds row (lane&15), k = (lane>>4)*8 + i
// B-frag (W rows=cols) : lane holds W[col=(lane&15)] at same k — row-major K both.
// C/D: col = lane&15, row = (lane>>4)*4 + reg   [verified layout, m89/m91]
__global__ __launch_bounds__(64) void gru_step(
    const unsigned short* __restrict__ xin,   // [SEQ*BATCH][HID] bf16 layer input
    const unsigned short* __restrict__ Wih,   // [3H][HID] bf16
    const unsigned short* __restrict__ Whh,   // [3H][HID] bf16
    const float* __restrict__ bih,            // [3H]
    const float* __restrict__ bhh,            // [3H]
    const float* __restrict__ hf_in,          // [BATCH][HID] f32 master
    float* __restrict__ hf_out,
    const unsigned short* __restrict__ hb_in, // [BATCH][HID] bf16 copy
    unsigned short* __restrict__ hb_out,
    unsigned short* __restrict__ ys_bf,       // layer0: next layer's input buf (or null)
    float* __restrict__ ys_f32,               // layer1: d_out ys (or null)
    float* __restrict__ state_out,            // non-null only at t == SEQ-1
    int t, int is_first)
{
  int lane = threadIdx.x;
  int rlo = lane & 15, kg = lane >> 4;
  int ct = blockIdx.x, bg = blockIdx.y;
  int c = ct * 16 + rlo;
  int k0 = kg * 8;

  f32x4 accr[4]  = {f32x4{0,0,0,0},f32x4{0,0,0,0},f32x4{0,0,0,0},f32x4{0,0,0,0}};
  f32x4 accz[4]  = {f32x4{0,0,0,0},f32x4{0,0,0,0},f32x4{0,0,0,0},f32x4{0,0,0,0}};
  f32x4 accin[4] = {f32x4{0,0,0,0},f32x4{0,0,0,0},f32x4{0,0,0,0},f32x4{0,0,0,0}};
  f32x4 acchn[4] = {f32x4{0,0,0,0},f32x4{0,0,0,0},f32x4{0,0,0,0},f32x4{0,0,0,0}};

  // ---- x part: gi contributions (r, z, inn) ----
  {
    const unsigned short* wr = Wih + (size_t)c * HID + k0;
    const unsigned short* wz = Wih + (size_t)(HID + c) * HID + k0;
    const unsigned short* wn = Wih + (size_t)(2*HID + c) * HID + k0;
    const unsigned short* xr = xin + ((size_t)t*BATCH + (size_t)bg*64 + rlo) * HID + k0;
    for (int ks = 0; ks < 32; ++ks){
      int o = ks * 32;
      bf16x8 w0 = ldbf8(wr + o), w1 = ldbf8(wz + o), w2 = ldbf8(wn + o);
      #pragma unroll
      for (int bt = 0; bt < 4; ++bt){
        bf16x8 a = ldbf8(xr + (size_t)bt*16*HID + o);
        accr[bt]  = __builtin_amdgcn_mfma_f32_16x16x32_bf16(a, w0, accr[bt], 0,0,0);
        accz[bt]  = __builtin_amdgcn_mfma_f32_16x16x32_bf16(a, w1, accz[bt], 0,0,0);
        accin[bt] = __builtin_amdgcn_mfma_f32_16x16x32_bf16(a, w2, accin[bt],0,0,0);
      }
    }
  }
  // ---- h part: gh contributions (r, z, hn) ----  (h == 0 at t==0: skip)
  if (!is_first){
    const unsigned short* vr = Whh + (size_t)c * HID + k0;
    const unsigned short* vz = Whh + (size_t)(HID + c) * HID + k0;
    const unsigned short* vn = Whh + (size_t)(2*HID + c) * HID + k0;
    const unsigned short* hr = hb_in + ((size_t)bg*64 + rlo) * HID + k0;
    for (int ks = 0; ks < 32; ++ks){
      int o = ks * 32;
      bf16x8 w0 = ldbf8(vr + o), w1 = ldbf8(vz + o), w2 = ldbf8(vn + o);
      #pragma unroll
      for (int bt = 0; bt < 4; ++bt){
        bf16x8 a = ldbf8(hr + (size_t)bt*16*HID + o);
        accr[bt]  = __builtin_amdgcn_mfma_f32_16x16x32_bf16(a, w0, accr[bt], 0,0,0);
        accz[bt]  = __builtin_amdgcn_mfma_f32_16x16x32_bf16(a, w1, accz[bt], 0,0,0);
        acchn[bt] = __builtin_amdgcn_mfma_f32_16x16x32_bf16(a, w2, acchn[bt],0,0,0);
      }
    }
  }

  float br_ = bih[c]         + bhh[c];
  float bz_ = bih[HID + c]   + bhh[HID + c];
  float bi_ = bih[2*HID + c];
  float bh_ = bhh[2*HID + c];

  #pragma unroll
  for (int bt = 0; bt < 4; ++bt){
    #pragma unroll
    for (int r = 0; r < 4; ++r){
      int brow = bg*64 + bt*16 + kg*4 + r;
      float rg = sigm(accr[bt][r] + br_);
      float zg = sigm(accz[bt][r] + bz_);
      float ng = tanh_(accin[bt][r] + bi_ + rg * (acchn[bt][r] + bh_));
      float hold = is_first ? 0.0f : hf_in[(size_t)brow * HID + c];
      float hv = (1.0f - zg) * ng + zg * hold;
      size_t oidx = (size_t)brow * HID + c;
      hf_out[oidx] = hv;
      hb_out[oidx] = f2bf(hv);
      size_t yidx = ((size_t)t * BATCH + brow) * HID + c;
      if (ys_bf)  ys_bf[yidx] = f2bf(hv);
      if (ys_f32) ys_f32[yidx] = hv;
      if (state_out) state_out[oidx] = hv;
    }
  }
}

// ---------------- launch ----------------

extern "C" void kernel_launch(void* const* d_in, const int* in_sizes, int n_in,
                              void* d_out, int out_size, void* d_ws, size_t ws_size,
                              hipStream_t stream){
  (void)in_sizes; (void)n_in; (void)out_size; (void)ws_size;
  const int*   src  = (const int*)  d_in[0];
  const float* embW = (const float*)d_in[1];
  const float* Wih  = (const float*)d_in[2];
  const float* Whh  = (const float*)d_in[3];
  const float* bih  = (const float*)d_in[4];
  const float* bhh  = (const float*)d_in[5];
  float* out = (float*)d_out;

  char* ws = (char*)d_ws;
  size_t off = 0;
  auto carve = [&](size_t bytes) -> void* {
    void* p = ws + off;
    off += (bytes + 255) & ~(size_t)255;
    return p;
  };
  const size_t WELEM = (size_t)2 * H3 * HID;      // elems per weight tensor (both layers)
  unsigned short* wihb = (unsigned short*)carve(WELEM * 2);
  unsigned short* whhb = (unsigned short*)carve(WELEM * 2);
  unsigned short* x0   = (unsigned short*)carve((size_t)SEQ*BATCH*HID*2);
  unsigned short* x1   = (unsigned short*)carve((size_t)SEQ*BATCH*HID*2);
  float* hfA = (float*)carve((size_t)BATCH*HID*4);
  float* hfB = (float*)carve((size_t)BATCH*HID*4);
  unsigned short* hbA = (unsigned short*)carve((size_t)BATCH*HID*2);
  unsigned short* hbB = (unsigned short*)carve((size_t)BATCH*HID*2);
  float* hf[2] = {hfA, hfB};
  unsigned short* hb[2] = {hbA, hbB};

  cvt_bf16<<<2048, 256, 0, stream>>>(Wih, wihb, (int)(WELEM/4));
  cvt_bf16<<<2048, 256, 0, stream>>>(Whh, whhb, (int)(WELEM/4));
  embed_gather<<<SEQ*BATCH, 256, 0, stream>>>(src, embW, x0);

  float* state = out + (size_t)SEQ*BATCH*HID;
  for (int l = 0; l < 2; ++l){
    const unsigned short* xin = (l == 0) ? x0 : x1;
    const unsigned short* wl = wihb + (size_t)l*H3*HID;
    const unsigned short* vl = whhb + (size_t)l*H3*HID;
    for (int t = 0; t < SEQ; ++t){
      int cur = t & 1;
      gru_step<<<dim3(64, 2), 64, 0, stream>>>(
          xin, wl, vl, bih + l*H3, bhh + l*H3,
          hf[cur], hf[cur^1], hb[cur], hb[cur^1],
          (l == 0) ? x1 : nullptr,
          (l == 1) ? out : nullptr,
          (t == SEQ-1) ? (state + (size_t)l*BATCH*HID) : nullptr,
          t, (t == 0) ? 1 : 0);
    }
  }
}

// Round 2
// 6162.691 us; speedup vs baseline: 4.3834x; 4.3834x over previous
//
#include <hip/hip_runtime.h>
#include <cstdint>
#include <cstddef>

#define SEQ 256
#define BATCH 128
#define HID 1024
#define H3 3072
#define TCH 32                 // timesteps per gi chunk
#define CROWS (TCH*BATCH)      // 4096 rows per chunk GEMM

typedef __bf16 bf16x8 __attribute__((ext_vector_type(8)));
typedef float f32x4 __attribute__((ext_vector_type(4)));
typedef unsigned short ushort8 __attribute__((ext_vector_type(8)));

static __device__ __forceinline__ unsigned short f2bf(float f){
  unsigned int u = __float_as_uint(f);
  u += 0x7fffu + ((u >> 16) & 1u);
  return (unsigned short)(u >> 16);
}
static __device__ __forceinline__ float sigm(float x){
  return 1.0f / (1.0f + __expf(-x));
}
static __device__ __forceinline__ float tanh_(float x){
  x = fminf(15.0f, fmaxf(-15.0f, x));
  float e = __expf(2.0f * x);
  return (e - 1.0f) / (e + 1.0f);
}

// ---------------- prologue kernels ----------------

__global__ __launch_bounds__(256) void cvt_bf16(const float* __restrict__ in,
                                                unsigned short* __restrict__ out, int n4){
  int i = blockIdx.x * blockDim.x + threadIdx.x;
  int stride = gridDim.x * blockDim.x;
  for (; i < n4; i += stride){
    float4 v = reinterpret_cast<const float4*>(in)[i];
    ushort4 o = { f2bf(v.x), f2bf(v.y), f2bf(v.z), f2bf(v.w) };
    reinterpret_cast<ushort4*>(out)[i] = o;
  }
}

// x0[s*BATCH + b][e] = bf16(emb_W[source[b][s]][e])
__global__ __launch_bounds__(256) void embed_gather(const int* __restrict__ src,
                                                    const float* __restrict__ embW,
                                                    unsigned short* __restrict__ x0){
  int bx = blockIdx.x;            // = s*BATCH + b
  int s = bx >> 7, b = bx & 127;
  int row = src[b * SEQ + s];
  float4 v = reinterpret_cast<const float4*>(embW + (size_t)row * HID)[threadIdx.x];
  ushort4 o = { f2bf(v.x), f2bf(v.y), f2bf(v.z), f2bf(v.w) };
  reinterpret_cast<ushort4*>(x0 + (size_t)bx * HID)[threadIdx.x] = o;
}

// f32 rows -> bf16 rows (layer-1 chunk input from d_out)
__global__ __launch_bounds__(256) void cvt_rows(const float* __restrict__ in,
                                                unsigned short* __restrict__ out, int n4){
  int i = blockIdx.x * blockDim.x + threadIdx.x;
  int stride = gridDim.x * blockDim.x;
  for (; i < n4; i += stride){
    float4 v = reinterpret_cast<const float4*>(in)[i];
    ushort4 o = { f2bf(v.x), f2bf(v.y), f2bf(v.z), f2bf(v.w) };
    reinterpret_cast<ushort4*>(out)[i] = o;
  }
}

// ---------------- chunk GEMM: gi = A @ B^T ----------------
// A [CROWS][1024] bf16 row-major, B [3072][1024] bf16 row-major (N-major),
// C [CROWS][3072] f32.  128x128 tile, BK=32, reg-staged double-buffered LDS.
#define BM 128
#define BN 128
#define BK 32
#define LDT 40   // padded leading dim (elems) -> <=2-way LDS bank aliasing

__global__ __launch_bounds__(256) void gemm_xw(
    const unsigned short* __restrict__ A,
    const unsigned short* __restrict__ B,
    float* __restrict__ C)
{
  __shared__ unsigned short As[2][BM][LDT];
  __shared__ unsigned short Bs[2][BN][LDT];
  int tid = threadIdx.x;
  int lane = tid & 63, wid = tid >> 6;
  int fr = lane & 15, kg = lane >> 4;
  int wr = wid >> 1, wc = wid & 1;
  int brow = blockIdx.x * BM;
  int bcol = blockIdx.y * BN;

  // staging map: 512 chunks of 16B per tile; thread t owns chunks t and t+256
  int r0 = tid >> 2;                 // rows 0..63
  int r1 = 64 + (tid >> 2);          // rows 64..127
  int k8 = (tid & 3) * 8;

  const unsigned short* Ab = A + (size_t)brow * HID;
  const unsigned short* Bb = B + (size_t)bcol * HID;

  f32x4 acc[4][4] = {};
  ushort8 a0, a1, b0, b1;

  a0 = *(const ushort8*)(Ab + (size_t)r0 * HID + k8);
  a1 = *(const ushort8*)(Ab + (size_t)r1 * HID + k8);
  b0 = *(const ushort8*)(Bb + (size_t)r0 * HID + k8);
  b1 = *(const ushort8*)(Bb + (size_t)r1 * HID + k8);
  *(ushort8*)&As[0][r0][k8] = a0;
  *(ushort8*)&As[0][r1][k8] = a1;
  *(ushort8*)&Bs[0][r0][k8] = b0;
  *(ushort8*)&Bs[0][r1][k8] = b1;
  __syncthreads();

  for (int kt = 0; kt < HID / BK; ++kt){
    int cur = kt & 1;
    if (kt < HID / BK - 1){
      int ko = (kt + 1) * BK + k8;
      a0 = *(const ushort8*)(Ab + (size_t)r0 * HID + ko);
      a1 = *(const ushort8*)(Ab + (size_t)r1 * HID + ko);
      b0 = *(const ushort8*)(Bb + (size_t)r0 * HID + ko);
      b1 = *(const ushort8*)(Bb + (size_t)r1 * HID + ko);
    }
    bf16x8 af[4], bf[4];
    #pragma unroll
    for (int m = 0; m < 4; ++m)
      af[m] = *(const bf16x8*)&As[cur][wr*64 + m*16 + fr][kg*8];
    #pragma unroll
    for (int n = 0; n < 4; ++n)
      bf[n] = *(const bf16x8*)&Bs[cur][wc*64 + n*16 + fr][kg*8];
    #pragma unroll
    for (int m = 0; m < 4; ++m)
      #pragma unroll
      for (int n = 0; n < 4; ++n)
        acc[m][n] = __builtin_amdgcn_mfma_f32_16x16x32_bf16(af[m], bf[n], acc[m][n], 0,0,0);
    if (kt < HID / BK - 1){
      int nxt = cur ^ 1;
      *(ushort8*)&As[nxt][r0][k8] = a0;
      *(ushort8*)&As[nxt][r1][k8] = a1;
      *(ushort8*)&Bs[nxt][r0][k8] = b0;
      *(ushort8*)&Bs[nxt][r1][k8] = b1;
      __syncthreads();
    }
  }

  #pragma unroll
  for (int m = 0; m < 4; ++m){
    int row = brow + wr*64 + m*16 + kg*4;
    #pragma unroll
    for (int n = 0; n < 4; ++n){
      int col = bcol + wc*64 + n*16 + fr;
      float* cp = C + (size_t)row * H3 + col;
      #pragma unroll
      for (int q = 0; q < 4; ++q) cp[(size_t)q * H3] = acc[m][n][q];
    }
  }
}

// ---------------- one GRU time step (h-GEMM + elementwise) ----------------
// grid (64 ctiles, 2 rowgroups), 256 thr (4 waves x 16 rows).
// WG stages its 48x1024 Whh slice (r,z,n gates for 16 hidden cols) into LDS.
#define LDB 1032   // padded leading dim for 1024-elem rows

__global__ __launch_bounds__(256) void gru_step2(
    const unsigned short* __restrict__ Whh,   // layer's [3072][1024] bf16
    const float* __restrict__ bih,            // layer's [3072]
    const float* __restrict__ bhh,
    const unsigned short* __restrict__ hb_in, // [128][1024] bf16 h_{t-1}
    unsigned short* __restrict__ hb_out,
    float* __restrict__ out,                  // d_out base (ys region)
    const float* __restrict__ gi_t,           // [128][3072] f32 x-part
    float* __restrict__ state_out,            // null unless t == SEQ-1
    int t)
{
  __shared__ unsigned short Bsl[48 * LDB];    // 99 KB
  int tid = threadIdx.x;
  int lane = tid & 63, wid = tid >> 6;
  int fr = lane & 15, kg = lane >> 4;
  int ct = blockIdx.x, rg = blockIdx.y;
  int c = ct * 16 + fr;                       // hidden column
  int rowbase = rg * 64 + wid * 16;

  f32x4 acc[3] = {};
  if (t > 0){
    // burst-stage Whh slice: LDS row r (0..47) = Whh[(r>>4)*1024 + ct*16 + (r&15)]
    #pragma unroll
    for (int b = 0; b < 3; ++b){
      ushort8 rv[8];
      #pragma unroll
      for (int j = 0; j < 8; ++j){
        int cid = (b*8 + j) * 256 + tid;        // 0..6143
        int r = cid >> 7, k16 = cid & 127;
        int wrow = (r >> 4) * HID + ct * 16 + (r & 15);
        rv[j] = *(const ushort8*)(Whh + (size_t)wrow * HID + k16 * 8);
      }
      #pragma unroll
      for (int j = 0; j < 8; ++j){
        int cid = (b*8 + j) * 256 + tid;
        int r = cid >> 7, k16 = cid & 127;
        *(ushort8*)&Bsl[r * LDB + k16 * 8] = rv[j];
      }
    }
    __syncthreads();

    const unsigned short* hrow = hb_in + (size_t)(rowbase + fr) * HID + kg * 8;
    #pragma unroll 8
    for (int ks = 0; ks < 32; ++ks){
      bf16x8 a  = *(const bf16x8*)(hrow + ks * 32);
      bf16x8 b0 = *(const bf16x8*)&Bsl[(     fr) * LDB + ks*32 + kg*8];
      bf16x8 b1 = *(const bf16x8*)&Bsl[(16 + fr) * LDB + ks*32 + kg*8];
      bf16x8 b2 = *(const bf16x8*)&Bsl[(32 + fr) * LDB + ks*32 + kg*8];
      acc[0] = __builtin_amdgcn_mfma_f32_16x16x32_bf16(a, b0, acc[0], 0,0,0);
      acc[1] = __builtin_amdgcn_mfma_f32_16x16x32_bf16(a, b1, acc[1], 0,0,0);
      acc[2] = __builtin_amdgcn_mfma_f32_16x16x32_bf16(a, b2, acc[2], 0,0,0);
    }
  }

  float br_ = bih[c]       + bhh[c];
  float bz_ = bih[HID+c]   + bhh[HID+c];
  float bi_ = bih[2*HID+c];
  float bh_ = bhh[2*HID+c];

  #pragma unroll
  for (int q = 0; q < 4; ++q){
    int brow = rowbase + kg * 4 + q;
    const float* gp = gi_t + (size_t)brow * H3 + c;
    float gr = gp[0], gz = gp[HID], gn = gp[2*HID];
    float hold = (t > 0) ? out[((size_t)(t-1) * BATCH + brow) * HID + c] : 0.0f;
    float rg_ = sigm(gr + acc[0][q] + br_);
    float zg  = sigm(gz + acc[1][q] + bz_);
    float ng  = tanh_(gn + bi_ + rg_ * (acc[2][q] + bh_));
    float hv  = (1.0f - zg) * ng + zg * hold;
    out[((size_t)t * BATCH + brow) * HID + c] = hv;
    hb_out[(size_t)brow * HID + c] = f2bf(hv);
    if (state_out) state_out[(size_t)brow * HID + c] = hv;
  }
}

// ---------------- launch ----------------

extern "C" void kernel_launch(void* const* d_in, const int* in_sizes, int n_in,
                              void* d_out, int out_size, void* d_ws, size_t ws_size,
                              hipStream_t stream){
  (void)in_sizes; (void)n_in; (void)out_size; (void)ws_size;
  const int*   src  = (const int*)  d_in[0];
  const float* embW = (const float*)d_in[1];
  const float* Wih  = (const float*)d_in[2];
  const float* Whh  = (const float*)d_in[3];
  const float* bih  = (const float*)d_in[4];
  const float* bhh  = (const float*)d_in[5];
  float* out = (float*)d_out;

  char* ws = (char*)d_ws;
  size_t off = 0;
  auto carve = [&](size_t bytes) -> void* {
    void* p = ws + off;
    off += (bytes + 255) & ~(size_t)255;
    return p;
  };
  const size_t WELEM = (size_t)2 * H3 * HID;
  unsigned short* wihb = (unsigned short*)carve(WELEM * 2);
  unsigned short* whhb = (unsigned short*)carve(WELEM * 2);
  unsigned short* x0   = (unsigned short*)carve((size_t)SEQ*BATCH*HID*2);
  float*          gi   = (float*)         carve((size_t)CROWS*H3*4);
  unsigned short* ybc  = (unsigned short*)carve((size_t)CROWS*HID*2);
  unsigned short* hbA  = (unsigned short*)carve((size_t)BATCH*HID*2);
  unsigned short* hbB  = (unsigned short*)carve((size_t)BATCH*HID*2);
  unsigned short* hb[2] = {hbA, hbB};

  cvt_bf16<<<2048, 256, 0, stream>>>(Wih, wihb, (int)(WELEM/4));
  cvt_bf16<<<2048, 256, 0, stream>>>(Whh, whhb, (int)(WELEM/4));
  embed_gather<<<SEQ*BATCH, 256, 0, stream>>>(src, embW, x0);

  float* state = out + (size_t)SEQ*BATCH*HID;
  for (int l = 0; l < 2; ++l){
    const float* bihl = bih + l*H3;
    const float* bhhl = bhh + l*H3;
    const unsigned short* wl = wihb + (size_t)l*H3*HID;
    const unsigned short* vl = whhb + (size_t)l*H3*HID;
    for (int cch = 0; cch < SEQ/TCH; ++cch){
      const unsigned short* Achunk;
      if (l == 0){
        Achunk = x0 + (size_t)cch*CROWS*HID;
      } else {
        cvt_rows<<<2048, 256, 0, stream>>>(out + (size_t)cch*CROWS*HID, ybc,
                                           (int)((size_t)CROWS*HID/4));
        Achunk = ybc;
      }
      gemm_xw<<<dim3(CROWS/BM, H3/BN), 256, 0, stream>>>(Achunk, wl, gi);
      for (int k = 0; k < TCH; ++k){
        int tt = cch*TCH + k;
        int cur = tt & 1;
        gru_step2<<<dim3(64, 2), 256, 0, stream>>>(
            vl, bihl, bhhl, hb[cur], hb[cur^1], out,
            gi + (size_t)k*BATCH*H3,
            (tt == SEQ-1) ? (state + (size_t)l*BATCH*HID) : nullptr,
            tt);
      }
    }
  }
}